// Round 22
// baseline (79.157 us; speedup 1.0000x reference)
//
#include <hip/hip_runtime.h>
#include <math.h>

// TopK router via split-bf16 MFMA: logits = x @ W^T, top-2 + softmax.
// x = xh + xl (bf16 RTNE split via v_cvt_pk_bf16_f32, consume-side),
// W preconverted to ws (h/l bf16) by wprep. logits = xh*wh+xh*wl+xl*wh.
//
// Round-22 = r21 with 16 waves (1024 thr), 4 waves/SIMD.
// Wave = (kw 0..3, es 0..3): K32 window x 16-expert tile, acc[4][1],
// 12 MFMA/phase. TOK=64, grid 256 (1 block/CU), CK=128, 3x32KB DMA
// buffers (96KB LDS), depth-2 gload16 (pre-swizzled global source,
// linear LDS dest), plain per-phase s_barrier via the vmcnt-transitivity
// invariant: B(c) is issued before DMA(c+2) and after DMA(c+1), so the
// compiler's wait-for-B(c) before the MFMAs retires DMA(c+1) -> next
// phase's buffer is published at the barrier with NO vmcnt drain.
// Rationale: r21 ran 2 waves/SIMD; every residual latency was exposed.
// 4 waves/SIMD doubles TLP cover at the cost of 2x A-side ds_read/cvt
// (still under the per-phase HBM budget).

typedef float f32x4 __attribute__((ext_vector_type(4)));
typedef short bf16x8 __attribute__((ext_vector_type(8)));
typedef unsigned int u32;

#define NE 64
#define TOK 64
#define CK 128
#define THREADS 1024
#define LDE 68

__device__ __forceinline__ u32 cvtpk(float lo, float hi) {
  u32 r;
  asm("v_cvt_pk_bf16_f32 %0, %1, %2" : "=v"(r) : "v"(lo), "v"(hi));
  return r;
}
__device__ __forceinline__ float asf(u32 u) {
  return __builtin_bit_cast(float, u);
}
// 8 f32 -> packed bf16 high (hp) and low-residual (lp); residual exact.
__device__ __forceinline__ void cvt8(const f32x4 a, const f32x4 b,
                                     uint4& hp, uint4& lp) {
  hp.x = cvtpk(a.x, a.y);
  hp.y = cvtpk(a.z, a.w);
  hp.z = cvtpk(b.x, b.y);
  hp.w = cvtpk(b.z, b.w);
  lp.x = cvtpk(a.x - asf(hp.x << 16), a.y - asf(hp.x & 0xFFFF0000u));
  lp.y = cvtpk(a.z - asf(hp.y << 16), a.w - asf(hp.y & 0xFFFF0000u));
  lp.z = cvtpk(b.x - asf(hp.z << 16), b.y - asf(hp.z & 0xFFFF0000u));
  lp.w = cvtpk(b.z - asf(hp.w << 16), b.w - asf(hp.w & 0xFFFF0000u));
}
// direct HBM->LDS, 16B per lane; LDS dest = wave-uniform base + lane*16
__device__ __forceinline__ void gload16(const void* gsrc, void* ldst) {
  __builtin_amdgcn_global_load_lds(
      (const __attribute__((address_space(1))) void*)gsrc,
      (__attribute__((address_space(3))) void*)ldst, 16, 0, 0);
}

__global__ __launch_bounds__(256)
void wprep(const float* __restrict__ Wg, uint2* __restrict__ Who,
           uint2* __restrict__ Wlo) {
  const int i = blockIdx.x * 256 + threadIdx.x;   // f32x4 index (65536 total)
  const f32x4 v = *((const f32x4*)Wg + i);
  uint2 hp, lp;
  hp.x = cvtpk(v.x, v.y);
  hp.y = cvtpk(v.z, v.w);
  lp.x = cvtpk(v.x - asf(hp.x << 16), v.y - asf(hp.x & 0xFFFF0000u));
  lp.y = cvtpk(v.z - asf(hp.y << 16), v.w - asf(hp.y & 0xFFFF0000u));
  Who[i] = hp;
  Wlo[i] = lp;
}

__global__ __launch_bounds__(THREADS, 4)
void gemm_topk(const float* __restrict__ x, const u32* __restrict__ Whg,
               const u32* __restrict__ Wlg, float* __restrict__ out_probs,
               float* __restrict__ out_idx, int D) {
  // 3 fp32 x-buffers of 32KB (64 rows x 512B); epilogue reuses first 64KB
  __shared__ __align__(16) char smem[98304];

  const int tid = threadIdx.x;
  const int w   = tid >> 6;        // 0..15
  const int l   = tid & 63;
  const int kw  = w & 3;           // K32 window within chunk
  const int es  = w >> 2;          // expert 16-tile (0..3)
  const int m0  = blockIdx.x * TOK;
  const int nCh = D / CK;          // 32
  const int Du  = D / 2;           // u32 per W row

  const int g   = l >> 4;          // k sub-group
  const int r16 = l & 15;

  // ---- staging map: DMA round j (0..1): row = 2w + (l>>5) + 32j.
  // LDS dest linear (uniform base + lane*16); GLOBAL source pre-swizzled.
  const int rbase = 2 * w + (l >> 5);             // 0..31
  const int bsw   = (l & 31) ^ (rbase & 7);       // (32j)&7==0 -> same both j
  const float* gX = x + (size_t)(m0 + rbase) * D + bsw * 4;
  const size_t jstep = (size_t)32 * D;            // +32 rows for round 1

  // ---- B fragment bases (u32 units), L2-hot direct-global
  const u32* whb = Whg + (size_t)(es * 16 + r16) * Du + kw * 16 + g * 4;
  const u32* wlb = Wlg + (size_t)(es * 16 + r16) * Du + kw * 16 + g * 4;

  // ---- A read offsets (swizzled, 16B granule), m-tile rows m*16+r16
  const int c0 = kw * 8 + g * 2;
  int aoff[4][2];
#pragma unroll
  for (int m = 0; m < 4; ++m) {
    const int row = m * 16 + r16;                 // row&7 == r16&7
    aoff[m][0] = row * 512 + ((c0       ^ (r16 & 7)) << 4);
    aoff[m][1] = row * 512 + (((c0 + 1) ^ (r16 & 7)) << 4);
  }

  f32x4 acc[4];
#pragma unroll
  for (int m = 0; m < 4; ++m) acc[m] = (f32x4){0.f, 0.f, 0.f, 0.f};

  // prologue: DMA chunks 0,1 -> bufs 0,1; wait chunk0 only (2 newest stay)
#pragma unroll
  for (int j = 0; j < 2; ++j)
    gload16(gX + jstep * j, smem + j * 16384 + w * 1024);
#pragma unroll
  for (int j = 0; j < 2; ++j)
    gload16(gX + jstep * j + CK, smem + 32768 + j * 16384 + w * 1024);
  asm volatile("s_waitcnt vmcnt(2)\n\ts_barrier" ::: "memory");

  for (int c = 0; c < nCh; ++c) {
    const int rb = (c % 3) * 32768;

    // B(c) first: older than DMA(c+2); compiler's B-wait before the MFMAs
    // transitively retires DMA(c+1) -> plain barrier suffices.
    const size_t ko = (size_t)c * (CK / 2);
    const bf16x8 bh = *(const bf16x8*)(whb + ko);
    const bf16x8 bl = *(const bf16x8*)(wlb + ko);

    // DMA-stage chunk c+2 (in flight ~2 full phases)
    if (c + 2 < nCh) {
      const int wb = ((c + 2) % 3) * 32768;
      const size_t co = (size_t)(c + 2) * CK;
#pragma unroll
      for (int j = 0; j < 2; ++j)
        gload16(gX + co + jstep * j, smem + wb + j * 16384 + w * 1024);
    }

    // A fragments: fp32 from LDS, cvt to bf16 h/l in-register
#pragma unroll
    for (int m = 0; m < 4; ++m) {
      const f32x4 t0 = *(const f32x4*)(smem + rb + aoff[m][0]);
      const f32x4 t1 = *(const f32x4*)(smem + rb + aoff[m][1]);
      uint4 hp, lp;
      cvt8(t0, t1, hp, lp);
      const bf16x8 ah = __builtin_bit_cast(bf16x8, hp);
      const bf16x8 al = __builtin_bit_cast(bf16x8, lp);
      acc[m] = __builtin_amdgcn_mfma_f32_16x16x32_bf16(ah, bh, acc[m], 0, 0, 0);
      acc[m] = __builtin_amdgcn_mfma_f32_16x16x32_bf16(ah, bl, acc[m], 0, 0, 0);
      acc[m] = __builtin_amdgcn_mfma_f32_16x16x32_bf16(al, bh, acc[m], 0, 0, 0);
    }

    // PLAIN barrier: no vmcnt drain; 3 buffers bound skew to 1 phase.
    asm volatile("s_barrier" ::: "memory");
  }

  __syncthreads();                  // settle before LDS reuse

  // ---- epilogue: reduce 4 k-windows, decode, top-2 ----
  float* R = (float*)smem;          // [16 waves][16 tr][64 lanes] = 64KB
#pragma unroll
  for (int m = 0; m < 4; ++m)
#pragma unroll
    for (int r = 0; r < 4; ++r)
      R[w * 1024 + (m * 4 + r) * 64 + l] = acc[m][r];
  __syncthreads();

  // 64 tok x 64 exp = 4096 values; 1024 threads x 4
  float vals[4];
  int dsti[4];
#pragma unroll
  for (int i = 0; i < 4; ++i) {
    const int j = tid + i * THREADS;
    const int t = j >> 6, e = j & 63;
    const int ee = e >> 4;                 // expert 16-tile
    const int mm = t >> 4, tr = t & 15;
    const int ll = (tr >> 2) * 16 + (e & 15);
    const int ri = (mm * 4 + (tr & 3)) * 64 + ll;
    float v = 0.f;
#pragma unroll
    for (int k = 0; k < 4; ++k)            // sum over kw windows
      v += R[(ee * 4 + k) * 1024 + ri];
    vals[i] = v;
    dsti[i] = t * LDE + e;
  }
  __syncthreads();                  // reads done before aliasing writes
  float* Lf = (float*)smem;         // [64][68]
#pragma unroll
  for (int i = 0; i < 4; ++i) Lf[dsti[i]] = vals[i];
  __syncthreads();

  if (tid < TOK) {
    const float* row = &Lf[tid * LDE];
    float b0 = -INFINITY, b1 = -INFINITY;
    int i0 = 0, i1 = 0;
#pragma unroll
    for (int e = 0; e < NE; ++e) {   // strict '>' = lowest index on ties
      const float val = row[e];
      if (val > b0) { b1 = b0; i1 = i0; b0 = val; i0 = e; }
      else if (val > b1) { b1 = val; i1 = e; }
    }
    const float e1  = expf(b1 - b0);
    const float inv = 1.f / (1.f + e1);
    const int tok = m0 + tid;
    out_probs[tok * 2 + 0] = inv;
    out_probs[tok * 2 + 1] = e1 * inv;
    out_idx[tok * 2 + 0] = (float)i0;
    out_idx[tok * 2 + 1] = (float)i1;
  }
}

// ---- fallback (round-6 fused VALU kernel) if ws is too small ----
#define FEW 8
#define FCK 64
#define FLDT 68
#define FTOK 64
__global__ __launch_bounds__(512, 2)
void router_fused(const float* __restrict__ x, const float* __restrict__ W,
                  float* __restrict__ out_probs, float* __restrict__ out_idx,
                  int D) {
  __shared__ float As[2][FTOK][FLDT];
  const int tid = threadIdx.x;
  const int w = __builtin_amdgcn_readfirstlane(tid >> 6);
  const int lane = tid & 63;
  const int m0 = blockIdx.x * FTOK;
  const int nCh = D / FCK;
  const float* xrow = x + (size_t)(m0 + lane) * D;
  const float* __restrict__ wbase = W + (size_t)(w * FEW) * D;
  float acc[FEW];
#pragma unroll
  for (int e = 0; e < FEW; ++e) acc[e] = 0.f;
  {
    const f32x4 a = *reinterpret_cast<const f32x4*>(xrow + 4 * w);
    const f32x4 b = *reinterpret_cast<const f32x4*>(xrow + 4 * (w + 8));
    *reinterpret_cast<f32x4*>(&As[0][lane][4 * w]) = a;
    *reinterpret_cast<f32x4*>(&As[0][lane][4 * (w + 8)]) = b;
  }
  __syncthreads();
  for (int c = 0; c < nCh; ++c) {
    const int buf = c & 1;
    f32x4 na, nb;
    const bool more = (c + 1 < nCh);
    if (more) {
      const float* xn = xrow + (size_t)(c + 1) * FCK;
      na = *reinterpret_cast<const f32x4*>(xn + 4 * w);
      nb = *reinterpret_cast<const f32x4*>(xn + 4 * (w + 8));
    }
    const float* __restrict__ wp = wbase + (size_t)c * FCK;
#pragma unroll 2
    for (int kk = 0; kk < FCK / 4; ++kk) {
      const f32x4 xvv = *reinterpret_cast<const f32x4*>(&As[buf][lane][kk * 4]);
#pragma unroll
      for (int e = 0; e < FEW; ++e) {
        const f32x4 wv = *reinterpret_cast<const f32x4*>(wp + (size_t)e * D + kk * 4);
        acc[e] = fmaf(xvv.x, wv.x, acc[e]);
        acc[e] = fmaf(xvv.y, wv.y, acc[e]);
        acc[e] = fmaf(xvv.z, wv.z, acc[e]);
        acc[e] = fmaf(xvv.w, wv.w, acc[e]);
      }
    }
    __syncthreads();
    if (more) {
      *reinterpret_cast<f32x4*>(&As[buf ^ 1][lane][4 * w]) = na;
      *reinterpret_cast<f32x4*>(&As[buf ^ 1][lane][4 * (w + 8)]) = nb;
    }
    __syncthreads();
  }
  float* L = &As[0][0][0];
  *reinterpret_cast<f32x4*>(&L[lane * FLDT + w * FEW + 0]) =
      (f32x4){acc[0], acc[1], acc[2], acc[3]};
  *reinterpret_cast<f32x4*>(&L[lane * FLDT + w * FEW + 4]) =
      (f32x4){acc[4], acc[5], acc[6], acc[7]};
  __syncthreads();
  if (tid < FTOK) {
    const float* row = &L[tid * FLDT];
    float b0 = -INFINITY, b1 = -INFINITY;
    int i0 = 0, i1 = 0;
#pragma unroll
    for (int e = 0; e < NE; ++e) {
      const float val = row[e];
      if (val > b0) { b1 = b0; i1 = i0; b0 = val; i0 = e; }
      else if (val > b1) { b1 = val; i1 = e; }
    }
    const float e1 = expf(b1 - b0);
    const float inv = 1.f / (1.f + e1);
    const int tok = m0 + tid;
    out_probs[tok * 2 + 0] = inv;
    out_probs[tok * 2 + 1] = e1 * inv;
    out_idx[tok * 2 + 0] = (float)i0;
    out_idx[tok * 2 + 1] = (float)i1;
  }
}

extern "C" void kernel_launch(void* const* d_in, const int* in_sizes, int n_in,
                              void* d_out, int out_size, void* d_ws, size_t ws_size,
                              hipStream_t stream) {
  const float* x = (const float*)d_in[0];
  const float* W = (const float*)d_in[1];

  const int E = 64;
  const int D = in_sizes[1] / E;            // 4096
  const int nTok = in_sizes[0] / D;         // 16384

  float* probs = (float*)d_out;
  float* idxo  = (float*)d_out + (size_t)nTok * 2;

  const size_t wBytes = (size_t)E * D * sizeof(short);   // 512 KB per half
  if (ws_size >= 2 * wBytes) {
    u32* Wh = (u32*)d_ws;
    u32* Wl = (u32*)((char*)d_ws + wBytes);
    hipLaunchKernelGGL(wprep, dim3((E * D / 4) / 256), dim3(256), 0, stream,
                       W, (uint2*)Wh, (uint2*)Wl);
    hipLaunchKernelGGL(gemm_topk, dim3(nTok / TOK), dim3(THREADS), 0, stream,
                       x, Wh, Wl, probs, idxo, D);
  } else {
    hipLaunchKernelGGL(router_fused, dim3(nTok / FTOK), dim3(512), 0, stream,
                       x, W, probs, idxo, D);
  }
}

// Round 23
// 69.890 us; speedup vs baseline: 1.1326x; 1.1326x over previous
//
#include <hip/hip_runtime.h>
#include <math.h>

// TopK router via split-bf16 MFMA: logits = x @ W^T, top-2 + softmax.
// x = xh + xl (bf16 RTNE split via v_cvt_pk_bf16_f32, consume-side),
// W preconverted to ws (h/l bf16) by wprep. logits = xh*wh+xh*wl+xl*wh.
//
// Round-23 = r21 (best, 76.0us) with HALVED barrier count.
// 4 LDS x-buffers (c&3, 128KB total) and s_barrier only after ODD chunks
// (16 barriers instead of 32). Race-freedom: within a 2-phase interval
// waves skew <=1 phase; DMA(c+2) (phase c) and DMA(c+3) (phase c+1)
// write bufs (c+2)&3 / (c+3)&3 — disjoint from the two live read bufs
// c&3 / (c+1)&3. Publication without a barrier: B(c) is issued after
// DMA(c+1) and before DMA(c+2), so the compiler's wait-for-B(c) (in-order
// vmem retirement) retires DMA(c+1) before phase c+1's reads.
// Everything else identical to r21: TOK=64, grid 256 (1 block/CU),
// 8 waves (kw 0..3, eh 0..1), 4 m-tiles (acc[4][2], 24 MFMA/phase),
// CK=128, depth-2 gload16 with pre-swizzled global source, B direct L2.

typedef float f32x4 __attribute__((ext_vector_type(4)));
typedef short bf16x8 __attribute__((ext_vector_type(8)));
typedef unsigned int u32;

#define NE 64
#define TOK 64
#define CK 128
#define THREADS 512
#define LDE 68

__device__ __forceinline__ u32 cvtpk(float lo, float hi) {
  u32 r;
  asm("v_cvt_pk_bf16_f32 %0, %1, %2" : "=v"(r) : "v"(lo), "v"(hi));
  return r;
}
__device__ __forceinline__ float asf(u32 u) {
  return __builtin_bit_cast(float, u);
}
// 8 f32 -> packed bf16 high (hp) and low-residual (lp); residual exact.
__device__ __forceinline__ void cvt8(const f32x4 a, const f32x4 b,
                                     uint4& hp, uint4& lp) {
  hp.x = cvtpk(a.x, a.y);
  hp.y = cvtpk(a.z, a.w);
  hp.z = cvtpk(b.x, b.y);
  hp.w = cvtpk(b.z, b.w);
  lp.x = cvtpk(a.x - asf(hp.x << 16), a.y - asf(hp.x & 0xFFFF0000u));
  lp.y = cvtpk(a.z - asf(hp.y << 16), a.w - asf(hp.y & 0xFFFF0000u));
  lp.z = cvtpk(b.x - asf(hp.z << 16), b.y - asf(hp.z & 0xFFFF0000u));
  lp.w = cvtpk(b.z - asf(hp.w << 16), b.w - asf(hp.w & 0xFFFF0000u));
}
// direct HBM->LDS, 16B per lane; LDS dest = wave-uniform base + lane*16
__device__ __forceinline__ void gload16(const void* gsrc, void* ldst) {
  __builtin_amdgcn_global_load_lds(
      (const __attribute__((address_space(1))) void*)gsrc,
      (__attribute__((address_space(3))) void*)ldst, 16, 0, 0);
}

__global__ __launch_bounds__(256)
void wprep(const float* __restrict__ Wg, uint2* __restrict__ Who,
           uint2* __restrict__ Wlo) {
  const int i = blockIdx.x * 256 + threadIdx.x;   // f32x4 index (65536 total)
  const f32x4 v = *((const f32x4*)Wg + i);
  uint2 hp, lp;
  hp.x = cvtpk(v.x, v.y);
  hp.y = cvtpk(v.z, v.w);
  lp.x = cvtpk(v.x - asf(hp.x << 16), v.y - asf(hp.x & 0xFFFF0000u));
  lp.y = cvtpk(v.z - asf(hp.y << 16), v.w - asf(hp.y & 0xFFFF0000u));
  Who[i] = hp;
  Wlo[i] = lp;
}

__global__ __launch_bounds__(THREADS, 2)
void gemm_topk(const float* __restrict__ x, const u32* __restrict__ Whg,
               const u32* __restrict__ Wlg, float* __restrict__ out_probs,
               float* __restrict__ out_idx, int D) {
  // 4 fp32 x-buffers of 32KB (64 rows x 512B); epilogue reuses first 64KB
  __shared__ __align__(16) char smem[131072];

  const int tid = threadIdx.x;
  const int w   = tid >> 6;
  const int l   = tid & 63;
  const int kw  = w & 3;           // K32 window within chunk
  const int eh  = w >> 2;          // expert half (0/1)
  const int m0  = blockIdx.x * TOK;
  const int nCh = D / CK;          // 32 (even)
  const int Du  = D / 2;           // u32 per W row

  const int g   = l >> 4;          // k sub-group
  const int r16 = l & 15;

  // ---- staging map: DMA round j (0..3) covers rows j*16 + 2w + (l>>5).
  // LDS dest linear (uniform base + lane*16); GLOBAL source pre-swizzled.
  const int rbase = 2 * w + (l >> 5);             // 0..15
  const int bsw   = (l & 31) ^ (rbase & 7);       // row&7 == rbase&7 all j
  const float* gX = x + (size_t)(m0 + rbase) * D + bsw * 4;
  const size_t jstep = (size_t)16 * D;            // +16 rows per round

  // ---- B fragment bases (u32 units), L2-hot direct-global
  const u32* wh0 = Whg + (size_t)(eh * 32 + 0  + r16) * Du + kw * 16 + g * 4;
  const u32* wh1 = Whg + (size_t)(eh * 32 + 16 + r16) * Du + kw * 16 + g * 4;
  const u32* wl0 = Wlg + (size_t)(eh * 32 + 0  + r16) * Du + kw * 16 + g * 4;
  const u32* wl1 = Wlg + (size_t)(eh * 32 + 16 + r16) * Du + kw * 16 + g * 4;

  // ---- A read offsets (swizzled, 16B granule), m-tile rows m*16+r16
  const int c0 = kw * 8 + g * 2;
  int aoff[4][2];
#pragma unroll
  for (int m = 0; m < 4; ++m) {
    const int row = m * 16 + r16;                 // row&7 == r16&7
    aoff[m][0] = row * 512 + ((c0       ^ (r16 & 7)) << 4);
    aoff[m][1] = row * 512 + (((c0 + 1) ^ (r16 & 7)) << 4);
  }

  f32x4 acc[4][2];
#pragma unroll
  for (int m = 0; m < 4; ++m)
#pragma unroll
    for (int n = 0; n < 2; ++n) acc[m][n] = (f32x4){0.f, 0.f, 0.f, 0.f};

  // prologue: DMA chunks 0,1 -> bufs 0,1; wait chunk0 only (4 newest stay)
#pragma unroll
  for (int j = 0; j < 4; ++j)
    gload16(gX + jstep * j, smem + j * 8192 + w * 1024);
#pragma unroll
  for (int j = 0; j < 4; ++j)
    gload16(gX + jstep * j + CK, smem + 32768 + j * 8192 + w * 1024);
  asm volatile("s_waitcnt vmcnt(4)\n\ts_barrier" ::: "memory");

  for (int c = 0; c < nCh; ++c) {
    const int rb = (c & 3) * 32768;

    // B(c) first: newer than DMA(c+1), older than DMA(c+2); its wait
    // retires DMA(c+1) -> phase c+1's buffer is published barrier-free.
    const size_t ko = (size_t)c * (CK / 2);
    const bf16x8 bh0 = *(const bf16x8*)(wh0 + ko);
    const bf16x8 bh1 = *(const bf16x8*)(wh1 + ko);
    const bf16x8 bl0 = *(const bf16x8*)(wl0 + ko);
    const bf16x8 bl1 = *(const bf16x8*)(wl1 + ko);

    // DMA-stage chunk c+2 -> buf (c+2)&3 (disjoint from live read bufs)
    if (c + 2 < nCh) {
      const int wb = ((c + 2) & 3) * 32768;
      const size_t co = (size_t)(c + 2) * CK;
#pragma unroll
      for (int j = 0; j < 4; ++j)
        gload16(gX + co + jstep * j, smem + wb + j * 8192 + w * 1024);
    }

    // A fragments: fp32 from LDS, cvt to bf16 h/l in-register
    bf16x8 ah[4], al[4];
#pragma unroll
    for (int m = 0; m < 4; ++m) {
      const f32x4 t0 = *(const f32x4*)(smem + rb + aoff[m][0]);
      const f32x4 t1 = *(const f32x4*)(smem + rb + aoff[m][1]);
      uint4 hp, lp;
      cvt8(t0, t1, hp, lp);
      ah[m] = __builtin_bit_cast(bf16x8, hp);
      al[m] = __builtin_bit_cast(bf16x8, lp);
    }
#pragma unroll
    for (int m = 0; m < 4; ++m) {
      acc[m][0] = __builtin_amdgcn_mfma_f32_16x16x32_bf16(ah[m], bh0, acc[m][0], 0, 0, 0);
      acc[m][0] = __builtin_amdgcn_mfma_f32_16x16x32_bf16(ah[m], bl0, acc[m][0], 0, 0, 0);
      acc[m][0] = __builtin_amdgcn_mfma_f32_16x16x32_bf16(al[m], bh0, acc[m][0], 0, 0, 0);
      acc[m][1] = __builtin_amdgcn_mfma_f32_16x16x32_bf16(ah[m], bh1, acc[m][1], 0, 0, 0);
      acc[m][1] = __builtin_amdgcn_mfma_f32_16x16x32_bf16(ah[m], bl1, acc[m][1], 0, 0, 0);
      acc[m][1] = __builtin_amdgcn_mfma_f32_16x16x32_bf16(al[m], bh1, acc[m][1], 0, 0, 0);
    }

    // barrier only after ODD chunks: skew bounded to 1 phase; 4 buffers
    // keep all writers disjoint from both live read buffers.
    if (c & 1) asm volatile("s_barrier" ::: "memory");
  }

  __syncthreads();                  // settle before LDS reuse

  // ---- epilogue: reduce 4 k-windows, decode, top-2 ----
  float* R = (float*)smem;          // [8 waves][32 tr][64 lanes] = 64KB
#pragma unroll
  for (int m = 0; m < 4; ++m)
#pragma unroll
    for (int n = 0; n < 2; ++n)
#pragma unroll
      for (int r = 0; r < 4; ++r)
        R[w * 2048 + ((m * 2 + n) * 4 + r) * 64 + l] = acc[m][n][r];
  __syncthreads();

  // 64 tok x 64 exp = 4096 values; 512 threads x 8
  float vals[8];
  int dsti[8];
#pragma unroll
  for (int i = 0; i < 8; ++i) {
    const int j = tid + i * THREADS;
    const int t = j >> 6, e = j & 63;
    const int mm = t >> 4, nn = (e >> 4) & 1, ee = e >> 5;
    const int rr = t & 3;
    const int ll = ((t & 15) >> 2) * 16 + (e & 15);
    float v = 0.f;
#pragma unroll
    for (int k = 0; k < 4; ++k)
      v += R[(ee * 4 + k) * 2048 + ((mm * 2 + nn) * 4 + rr) * 64 + ll];
    vals[i] = v;
    dsti[i] = t * LDE + e;
  }
  __syncthreads();                  // reads done before aliasing writes
  float* Lf = (float*)smem;         // [64][68]
#pragma unroll
  for (int i = 0; i < 8; ++i) Lf[dsti[i]] = vals[i];
  __syncthreads();

  if (tid < TOK) {
    const float* row = &Lf[tid * LDE];
    float b0 = -INFINITY, b1 = -INFINITY;
    int i0 = 0, i1 = 0;
#pragma unroll
    for (int e = 0; e < NE; ++e) {   // strict '>' = lowest index on ties
      const float val = row[e];
      if (val > b0) { b1 = b0; i1 = i0; b0 = val; i0 = e; }
      else if (val > b1) { b1 = val; i1 = e; }
    }
    const float e1  = expf(b1 - b0);
    const float inv = 1.f / (1.f + e1);
    const int tok = m0 + tid;
    out_probs[tok * 2 + 0] = inv;
    out_probs[tok * 2 + 1] = e1 * inv;
    out_idx[tok * 2 + 0] = (float)i0;
    out_idx[tok * 2 + 1] = (float)i1;
  }
}

// ---- fallback (round-6 fused VALU kernel) if ws is too small ----
#define FEW 8
#define FCK 64
#define FLDT 68
#define FTOK 64
__global__ __launch_bounds__(512, 2)
void router_fused(const float* __restrict__ x, const float* __restrict__ W,
                  float* __restrict__ out_probs, float* __restrict__ out_idx,
                  int D) {
  __shared__ float As[2][FTOK][FLDT];
  const int tid = threadIdx.x;
  const int w = __builtin_amdgcn_readfirstlane(tid >> 6);
  const int lane = tid & 63;
  const int m0 = blockIdx.x * FTOK;
  const int nCh = D / FCK;
  const float* xrow = x + (size_t)(m0 + lane) * D;
  const float* __restrict__ wbase = W + (size_t)(w * FEW) * D;
  float acc[FEW];
#pragma unroll
  for (int e = 0; e < FEW; ++e) acc[e] = 0.f;
  {
    const f32x4 a = *reinterpret_cast<const f32x4*>(xrow + 4 * w);
    const f32x4 b = *reinterpret_cast<const f32x4*>(xrow + 4 * (w + 8));
    *reinterpret_cast<f32x4*>(&As[0][lane][4 * w]) = a;
    *reinterpret_cast<f32x4*>(&As[0][lane][4 * (w + 8)]) = b;
  }
  __syncthreads();
  for (int c = 0; c < nCh; ++c) {
    const int buf = c & 1;
    f32x4 na, nb;
    const bool more = (c + 1 < nCh);
    if (more) {
      const float* xn = xrow + (size_t)(c + 1) * FCK;
      na = *reinterpret_cast<const f32x4*>(xn + 4 * w);
      nb = *reinterpret_cast<const f32x4*>(xn + 4 * (w + 8));
    }
    const float* __restrict__ wp = wbase + (size_t)c * FCK;
#pragma unroll 2
    for (int kk = 0; kk < FCK / 4; ++kk) {
      const f32x4 xvv = *reinterpret_cast<const f32x4*>(&As[buf][lane][kk * 4]);
#pragma unroll
      for (int e = 0; e < FEW; ++e) {
        const f32x4 wv = *reinterpret_cast<const f32x4*>(wp + (size_t)e * D + kk * 4);
        acc[e] = fmaf(xvv.x, wv.x, acc[e]);
        acc[e] = fmaf(xvv.y, wv.y, acc[e]);
        acc[e] = fmaf(xvv.z, wv.z, acc[e]);
        acc[e] = fmaf(xvv.w, wv.w, acc[e]);
      }
    }
    __syncthreads();
    if (more) {
      *reinterpret_cast<f32x4*>(&As[buf ^ 1][lane][4 * w]) = na;
      *reinterpret_cast<f32x4*>(&As[buf ^ 1][lane][4 * (w + 8)]) = nb;
    }
    __syncthreads();
  }
  float* L = &As[0][0][0];
  *reinterpret_cast<f32x4*>(&L[lane * FLDT + w * FEW + 0]) =
      (f32x4){acc[0], acc[1], acc[2], acc[3]};
  *reinterpret_cast<f32x4*>(&L[lane * FLDT + w * FEW + 4]) =
      (f32x4){acc[4], acc[5], acc[6], acc[7]};
  __syncthreads();
  if (tid < FTOK) {
    const float* row = &L[tid * FLDT];
    float b0 = -INFINITY, b1 = -INFINITY;
    int i0 = 0, i1 = 0;
#pragma unroll
    for (int e = 0; e < NE; ++e) {
      const float val = row[e];
      if (val > b0) { b1 = b0; i1 = i0; b0 = val; i0 = e; }
      else if (val > b1) { b1 = val; i1 = e; }
    }
    const float e1 = expf(b1 - b0);
    const float inv = 1.f / (1.f + e1);
    const int tok = m0 + tid;
    out_probs[tok * 2 + 0] = inv;
    out_probs[tok * 2 + 1] = e1 * inv;
    out_idx[tok * 2 + 0] = (float)i0;
    out_idx[tok * 2 + 1] = (float)i1;
  }
}

extern "C" void kernel_launch(void* const* d_in, const int* in_sizes, int n_in,
                              void* d_out, int out_size, void* d_ws, size_t ws_size,
                              hipStream_t stream) {
  const float* x = (const float*)d_in[0];
  const float* W = (const float*)d_in[1];

  const int E = 64;
  const int D = in_sizes[1] / E;            // 4096
  const int nTok = in_sizes[0] / D;         // 16384

  float* probs = (float*)d_out;
  float* idxo  = (float*)d_out + (size_t)nTok * 2;

  const size_t wBytes = (size_t)E * D * sizeof(short);   // 512 KB per half
  if (ws_size >= 2 * wBytes) {
    u32* Wh = (u32*)d_ws;
    u32* Wl = (u32*)((char*)d_ws + wBytes);
    hipLaunchKernelGGL(wprep, dim3((E * D / 4) / 256), dim3(256), 0, stream,
                       W, (uint2*)Wh, (uint2*)Wl);
    hipLaunchKernelGGL(gemm_topk, dim3(nTok / TOK), dim3(THREADS), 0, stream,
                       x, Wh, Wl, probs, idxo, D);
  } else {
    hipLaunchKernelGGL(router_fused, dim3(nTok / FTOK), dim3(512), 0, stream,
                       x, W, probs, idxo, D);
  }
}